// Round 5
// baseline (36.786 us; speedup 1.0000x reference)
//
#include <hip/hip_runtime.h>
#include <hip/hip_bf16.h>

// Problem constants (fixed by the reference).
#define M_ROWS 8192
#define K_DIM 128
#define NBINS 64           // label bins (labels 0..19; padded pow2, masked)
#define NCHUNK 8           // column-range splits across the grid
#define NRB2 64            // M / 128 row-blocks
#define TILES_PER_CHUNK 8  // 1024-col chunk / 128-col tiles
#define NPART (NCHUNK * 2) // partial sums per row: chunks x 2 col-waves

// C = 5 * log2(e): score in log2 domain is acc * C. exp(sim - m) = exp2(acc*C - m2).
#define C_LOG2 7.213475204444817f
#define INV_C 0.1386294361119891f
#define FLUSH_THR 160.0f  // exp2(x) == +0.0f for x < -150; 160 adds margin

typedef __attribute__((ext_vector_type(8))) short bf16x8;
typedef __attribute__((ext_vector_type(16))) float f32x16;

// Workspace layout (bytes).
#define FB16_OFF 0
#define RN2_OFF (M_ROWS * K_DIM * 2)         // 2 MB bf16 features
#define PS_OFF (RN2_OFF + M_ROWS * 4)        // +32 KB row-seed (log2 domain)
#define CNT_OFF (PS_OFF + NPART * M_ROWS * 4)
#define SUM_OFF (CNT_OFF + NBINS * 4)
#define DONE_OFF (SUM_OFF + 2 * 4)

__device__ __forceinline__ unsigned short f2bf(float f) {
  union { float f; unsigned int u; } v;
  v.f = f;
  unsigned int r = v.u + 0x7FFFu + ((v.u >> 16) & 1u);  // RNE
  return (unsigned short)(r >> 16);
}

__device__ __forceinline__ void gload_lds16(const unsigned short* g,
                                            unsigned short* l) {
  __builtin_amdgcn_global_load_lds(
      (const __attribute__((address_space(1))) void*)g,
      (__attribute__((address_space(3))) void*)l, 16, 0, 0);
}

// f32 -> bf16 convert fused with row-norm seed rn2[i] = C * ||f_i||^2.
// Block 0 additionally zeroes cnt/sums/done.
__global__ __launch_bounds__(256) void k_convert(const float* __restrict__ src,
                                                 unsigned short* __restrict__ dst,
                                                 float* __restrict__ rn2,
                                                 int* __restrict__ cnt,
                                                 float* __restrict__ sums,
                                                 unsigned int* __restrict__ done) {
  if (blockIdx.x == 0) {
    const int t = threadIdx.x;
    if (t < NBINS) cnt[t] = 0;
    if (t >= NBINS && t < NBINS + 2) sums[t - NBINS] = 0.f;
    if (t == NBINS + 2) *done = 0u;
  }
  const int wid = threadIdx.x >> 6;
  const int lane = threadIdx.x & 63;
  const int half = lane >> 5;
  const int l5 = lane & 31;
  const int row = blockIdx.x * 8 + wid * 2 + half;
  const int base = row * K_DIM + l5 * 4;
  const float4 v = *reinterpret_cast<const float4*>(&src[base]);
  ushort4 o;
  o.x = f2bf(v.x);
  o.y = f2bf(v.y);
  o.z = f2bf(v.z);
  o.w = f2bf(v.w);
  *reinterpret_cast<ushort4*>(&dst[base]) = o;
  float sq = v.x * v.x + v.y * v.y + v.z * v.z + v.w * v.w;
  sq += __shfl_xor(sq, 1);
  sq += __shfl_xor(sq, 2);
  sq += __shfl_xor(sq, 4);
  sq += __shfl_xor(sq, 8);
  sq += __shfl_xor(sq, 16);
  if (l5 == 0) rn2[row] = sq * C_LOG2;
}

// Parallel label histogram: 32 blocks, LDS pre-reduce, global atomic merge.
__global__ __launch_bounds__(256) void k_hist(const int* __restrict__ labels,
                                              int* __restrict__ cnt) {
  __shared__ int h[NBINS];
  const int t = threadIdx.x;
  if (t < NBINS) h[t] = 0;
  __syncthreads();
  const int i = blockIdx.x * 256 + t;
  atomicAdd(&h[labels[i] & (NBINS - 1)], 1);
  __syncthreads();
  if (t < NBINS && h[t]) atomicAdd(&cnt[t], h[t]);
}

// Fused sim + masked exp-sum, LDS-staged B, counted-vmcnt deep pipeline (T4)
// + setprio around MFMA (T5). Block = 4 waves (2 row x 2 col); block tile =
// 128x128 per step; wave tile = 64x64 as 2x2 32x32x16 MFMAs x 8 K-steps.
// Grid = 64 x 8 = 512 blocks (2 blocks/CU).
//
// Schedule per tile t (loads NEVER drain to 0 in-loop):
//   STAGE(cur^1, t+1)            // 8 gload_lds/wave, for tile t+1
//   s_waitcnt vmcnt(8)           // tile t's loads done; t+1's in flight
//   s_barrier                    // buf[cur] visible block-wide
//   setprio(1); ds_read+MFMA; setprio(0)
//   s_barrier                    // all waves done reading buf[cur]
//   flush-test + rare epilogue   // register-only, outside the barriers
//
// LDS B-tile layout: logical (col, slot16B) at byte col*256+(slot^(col&7))*16;
// linear LDS dest + inverse-swizzled GLOBAL source (rule 21); bank-exact:
// 8 consecutive cols hit 8 distinct 16B slots -> conflict-free ds_read_b128.
__global__ __launch_bounds__(256, 2) void k_main(
    const unsigned short* __restrict__ fb16, const int* __restrict__ labels,
    const float* __restrict__ rn2, float* __restrict__ ps) {
  __shared__ unsigned short lds[2][128 * 128];  // 2 x 32 KB

  const int tid = threadIdx.x;
  const int lane = tid & 63;
  const int wid = tid >> 6;
  const int wr = wid >> 1;
  const int wc = wid & 1;
  const int rb = (int)blockIdx.x % NRB2;
  const int chunk = (int)blockIdx.x / NRB2;
  const int l15 = lane & 15;
  const int lhi = lane >> 4;
  const int l31 = lane & 31;
  const int lh32 = lane >> 5;
  const int row0 = rb * 128 + wr * 64;
  const int col0 = chunk * 1024;

  // A fragments (32x32x16): lane holds A[l&31][(l>>5)*8 + e] per k-slice.
  bf16x8 a[2][8];
#pragma unroll
  for (int ri = 0; ri < 2; ++ri) {
    const int row = row0 + ri * 32 + l31;
#pragma unroll
    for (int ks = 0; ks < 8; ++ks)
      a[ri][ks] = *reinterpret_cast<const bf16x8*>(
          &fb16[row * K_DIM + ks * 16 + lh32 * 8]);
  }

  // Flush threshold (acc domain): if every acc < (min rn2 - 160)/C over the
  // wave's 64 rows, all exp2 terms are exact +0.0f.
  float thrMin = rn2[row0 + lane];
  thrMin = fminf(thrMin, __shfl_xor(thrMin, 1));
  thrMin = fminf(thrMin, __shfl_xor(thrMin, 2));
  thrMin = fminf(thrMin, __shfl_xor(thrMin, 4));
  thrMin = fminf(thrMin, __shfl_xor(thrMin, 8));
  thrMin = fminf(thrMin, __shfl_xor(thrMin, 16));
  thrMin = fminf(thrMin, __shfl_xor(thrMin, 32));
  const float thrAcc = (thrMin - FLUSH_THR) * INV_C;

  float s_st[2][16];
#pragma unroll
  for (int ri = 0; ri < 2; ++ri)
#pragma unroll
    for (int r = 0; r < 16; ++r) s_st[ri][r] = 0.f;

  // Staging: one 128x128 B-tile = 32 instr (8 per wave), 1 KB each.
#define STAGE(buf, t)                                                        \
  {                                                                          \
    const int colT_ = col0 + (t) * 128;                                      \
    _Pragma("unroll") for (int it = 0; it < 8; ++it) {                       \
      const int col_ = wid * 32 + it * 4 + lhi;                              \
      const int crow_ = colT_ + col_;                                        \
      gload_lds16(&fb16[crow_ * K_DIM + ((l15 ^ (col_ & 7)) << 3)],          \
                  &lds[buf][wid * 4096 + it * 512]);                         \
    }                                                                        \
  }

  STAGE(0, 0);

  int cur = 0;
#pragma unroll
  for (int t = 0; t < TILES_PER_CHUNK; ++t) {
    // Issue next tile's loads BEFORE waiting on this tile's (T14/T4 split),
    // then wait counted: this tile's 8 loads done, next tile's 8 in flight.
    if (t < TILES_PER_CHUNK - 1) {
      STAGE(cur ^ 1, t + 1);
      asm volatile("s_waitcnt vmcnt(8)" ::: "memory");
    } else {
      asm volatile("s_waitcnt vmcnt(0)" ::: "memory");
    }
    __builtin_amdgcn_s_barrier();

    f32x16 acc[2][2];
#pragma unroll
    for (int ri = 0; ri < 2; ++ri)
#pragma unroll
      for (int cj = 0; cj < 2; ++cj)
#pragma unroll
        for (int e = 0; e < 16; ++e) acc[ri][cj][e] = 0.f;

    const unsigned short* bufp = &lds[cur][0];
    __builtin_amdgcn_s_setprio(1);
#pragma unroll
    for (int ks = 0; ks < 8; ++ks) {
      bf16x8 b[2];
#pragma unroll
      for (int cj = 0; cj < 2; ++cj) {
        const int col = wc * 64 + cj * 32 + l31;
        const int phys = (ks * 2 + lh32) ^ (col & 7);
        b[cj] = *reinterpret_cast<const bf16x8*>(&bufp[col * 128 + phys * 8]);
      }
#pragma unroll
      for (int ri = 0; ri < 2; ++ri)
#pragma unroll
        for (int cj = 0; cj < 2; ++cj)
          acc[ri][cj] = __builtin_amdgcn_mfma_f32_32x32x16_bf16(
              a[ri][ks], b[cj], acc[ri][cj], 0, 0, 0);
    }
    __builtin_amdgcn_s_setprio(0);
    __builtin_amdgcn_s_barrier();  // all waves done reading buf[cur]

    // Flush test + rare epilogue: register-only, outside the barrier window.
    float mx = -INFINITY;
#pragma unroll
    for (int ri = 0; ri < 2; ++ri)
#pragma unroll
      for (int cj = 0; cj < 2; ++cj)
#pragma unroll
        for (int e = 0; e < 16; ++e) mx = fmaxf(mx, acc[ri][cj][e]);

    if (__any(mx >= thrAcc)) {
      // Diagonal tile: full masked exp2 against fixed row seeds.
      // C/D layout: col = lane&31, row = (r&3) + 8*(r>>2) + 4*(lane>>5).
      const int colT = col0 + t * 128 + wc * 64;
      int clab[2];
#pragma unroll
      for (int cj = 0; cj < 2; ++cj) clab[cj] = labels[colT + cj * 32 + l31];
#pragma unroll
      for (int ri = 0; ri < 2; ++ri) {
#pragma unroll
        for (int p = 0; p < 4; ++p) {
          const int rbase = row0 + ri * 32 + lh32 * 4 + p * 8;
          const float4 ms = *reinterpret_cast<const float4*>(&rn2[rbase]);
          const int4 rl = *reinterpret_cast<const int4*>(&labels[rbase]);
          const float msv[4] = {ms.x, ms.y, ms.z, ms.w};
          const int rlv[4] = {rl.x, rl.y, rl.z, rl.w};
#pragma unroll
          for (int q = 0; q < 4; ++q) {
            const int r = p * 4 + q;
            float pa = 0.f;
#pragma unroll
            for (int cj = 0; cj < 2; ++cj) {
              const float sc2 = acc[ri][cj][r] * C_LOG2 - msv[q];
              pa += (clab[cj] != rlv[q]) ? exp2f(sc2) : 0.f;
            }
            s_st[ri][r] += pa;
          }
        }
      }
    }
    cur ^= 1;
  }

  // One cross-lane reduction per wave at the end: sum over the 32 col-lanes.
#pragma unroll
  for (int ri = 0; ri < 2; ++ri)
#pragma unroll
    for (int r = 0; r < 16; ++r) {
      float p = s_st[ri][r];
      p += __shfl_xor(p, 1);
      p += __shfl_xor(p, 2);
      p += __shfl_xor(p, 4);
      p += __shfl_xor(p, 8);
      p += __shfl_xor(p, 16);
      s_st[ri][r] = p;
    }
  if (l31 == 0) {
    const int part = chunk * 2 + wc;
#pragma unroll
    for (int ri = 0; ri < 2; ++ri)
#pragma unroll
      for (int p = 0; p < 4; ++p) {
        float4 v = {s_st[ri][p * 4 + 0], s_st[ri][p * 4 + 1],
                    s_st[ri][p * 4 + 2], s_st[ri][p * 4 + 3]};
        *reinterpret_cast<float4*>(
            &ps[part * M_ROWS + row0 + ri * 32 + lh32 * 4 + p * 8]) = v;
      }
  }
}

// Merge partials -> per-row loss -> global sums; last block finalizes.
__global__ __launch_bounds__(256) void k_merge(
    const float* __restrict__ ps, const int* __restrict__ cnt,
    const int* __restrict__ labels, const float* __restrict__ ious,
    float* __restrict__ sums, unsigned int* __restrict__ done,
    float* __restrict__ out) {
  const int row = blockIdx.x * 256 + threadIdx.x;
  float ns = 0.f;
#pragma unroll
  for (int p = 0; p < NPART; ++p) ns += ps[p * M_ROWS + row];
  int pc = cnt[labels[row] & (NBINS - 1)] - 1;
  if (pc < 1) pc = 1;  // reference always has pos_cnt >= 1 here; avoid 0/0
  const float loss = ns / (float)pc;  // LAMDA = 1; loss = -log_prob
  const bool keep = ious[row] >= 0.5f;
  float lv = keep ? loss : 0.f;
  float kv = keep ? 1.f : 0.f;
#pragma unroll
  for (int off = 32; off >= 1; off >>= 1) {
    lv += __shfl_xor(lv, off);
    kv += __shfl_xor(kv, off);
  }
  __shared__ float slv[4], skv[4];
  const int lane = threadIdx.x & 63, wv = threadIdx.x >> 6;
  if (lane == 0) {
    slv[wv] = lv;
    skv[wv] = kv;
  }
  __syncthreads();
  if (threadIdx.x == 0) {
    atomicAdd(&sums[0], slv[0] + slv[1] + slv[2] + slv[3]);
    atomicAdd(&sums[1], skv[0] + skv[1] + skv[2] + skv[3]);
    __threadfence();
    const unsigned int old = atomicAdd(done, 1u);
    if (old == (unsigned int)(M_ROWS / 256 - 1)) {
      const float a = atomicAdd(&sums[0], 0.f);  // atomic read (L2-coherent)
      const float b = atomicAdd(&sums[1], 0.f);
      out[0] = a / fmaxf(b, 1.f);
    }
  }
}

extern "C" void kernel_launch(void* const* d_in, const int* in_sizes, int n_in,
                              void* d_out, int out_size, void* d_ws,
                              size_t ws_size, hipStream_t stream) {
  const float* feat = (const float*)d_in[0];
  const int* labels = (const int*)d_in[1];
  const float* ious = (const float*)d_in[2];
  float* out = (float*)d_out;
  char* ws = (char*)d_ws;
  unsigned short* fb16 = (unsigned short*)(ws + FB16_OFF);
  float* rn2 = (float*)(ws + RN2_OFF);
  float* ps = (float*)(ws + PS_OFF);
  int* cnt = (int*)(ws + CNT_OFF);
  float* sums = (float*)(ws + SUM_OFF);
  unsigned int* done = (unsigned int*)(ws + DONE_OFF);

  hipLaunchKernelGGL(k_convert, dim3(M_ROWS / 8), dim3(256), 0, stream, feat,
                     fb16, rn2, cnt, sums, done);
  hipLaunchKernelGGL(k_hist, dim3(M_ROWS / 256), dim3(256), 0, stream, labels,
                     cnt);
  hipLaunchKernelGGL(k_main, dim3(NRB2 * NCHUNK), dim3(256), 0, stream, fb16,
                     labels, rn2, ps);
  hipLaunchKernelGGL(k_merge, dim3(M_ROWS / 256), dim3(256), 0, stream, ps,
                     cnt, labels, ious, sums, done, out);
}

// Round 6
// 32.058 us; speedup vs baseline: 1.1475x; 1.1475x over previous
//
#include <hip/hip_runtime.h>
#include <hip/hip_bf16.h>

// Problem constants (fixed by the reference).
#define M_ROWS 8192
#define K_DIM 128
#define NBINS 64    // label bins (labels 0..19; padded pow2, masked)
#define NBANDS 64   // 128-row bands
#define NPAIR 32    // band pairings (p <-> 63-p): 65 tiles each
#define NSEG 16     // segments per pairing stream (seg0: 5 tiles, rest 4)

// C = 5*log2(e): score in log2 domain is acc*C. exp(sim - m) = exp2(acc*C - m2).
#define C_LOG2 7.213475204444817f
#define INV_C 0.1386294361119891f
#define FLUSH_THR 160.0f  // exp2(x) == +0.0f for x < -150; 160 adds margin

typedef __attribute__((ext_vector_type(8))) short bf16x8;
typedef __attribute__((ext_vector_type(16))) float f32x16;

// Workspace layout (bytes). ~2.1 MB.
#define FB16_OFF 0
#define RN2_OFF (M_ROWS * K_DIM * 2)     // 2 MB bf16 features
#define NEG_OFF (RN2_OFF + M_ROWS * 4)   // +32 KB row seeds (log2 domain)
#define BMIN_OFF (NEG_OFF + M_ROWS * 4)  // +32 KB per-row neg_sum accumulator
#define CNT_OFF (BMIN_OFF + NBANDS * 4)
#define SUM_OFF (CNT_OFF + NBINS * 4)
#define DONE_OFF (SUM_OFF + 2 * 4)

__device__ __forceinline__ unsigned short f2bf(float f) {
  union { float f; unsigned int u; } v;
  v.f = f;
  unsigned int r = v.u + 0x7FFFu + ((v.u >> 16) & 1u);  // RNE
  return (unsigned short)(r >> 16);
}

__device__ __forceinline__ void gload_lds16(const unsigned short* g,
                                            unsigned short* l) {
  __builtin_amdgcn_global_load_lds(
      (const __attribute__((address_space(1))) void*)g,
      (__attribute__((address_space(3))) void*)l, 16, 0, 0);
}

// f32 -> bf16 convert fused with row-norm seed rn2[i] = C * ||f_i||^2, plus
// zeroing of this block's 8 rows of neg[]; block 0 zeroes cnt/sums/done.
__global__ __launch_bounds__(256) void k_convert(const float* __restrict__ src,
                                                 unsigned short* __restrict__ dst,
                                                 float* __restrict__ rn2,
                                                 float* __restrict__ neg,
                                                 int* __restrict__ cnt,
                                                 float* __restrict__ sums,
                                                 unsigned int* __restrict__ done) {
  if (blockIdx.x == 0) {
    const int t = threadIdx.x;
    if (t < NBINS) cnt[t] = 0;
    if (t >= NBINS && t < NBINS + 2) sums[t - NBINS] = 0.f;
    if (t == NBINS + 2) *done = 0u;
  }
  if (threadIdx.x < 8) neg[blockIdx.x * 8 + threadIdx.x] = 0.f;
  const int wid = threadIdx.x >> 6;
  const int lane = threadIdx.x & 63;
  const int half = lane >> 5;
  const int l5 = lane & 31;
  const int row = blockIdx.x * 8 + wid * 2 + half;
  const int base = row * K_DIM + l5 * 4;
  const float4 v = *reinterpret_cast<const float4*>(&src[base]);
  ushort4 o;
  o.x = f2bf(v.x);
  o.y = f2bf(v.y);
  o.z = f2bf(v.z);
  o.w = f2bf(v.w);
  *reinterpret_cast<ushort4*>(&dst[base]) = o;
  float sq = v.x * v.x + v.y * v.y + v.z * v.z + v.w * v.w;
  sq += __shfl_xor(sq, 1);
  sq += __shfl_xor(sq, 2);
  sq += __shfl_xor(sq, 4);
  sq += __shfl_xor(sq, 8);
  sq += __shfl_xor(sq, 16);
  if (l5 == 0) rn2[row] = sq * C_LOG2;
}

// Label histogram + per-128-row-band rn2 minima (rn2 > 0, so int-bit compare
// preserves float order). Runs after k_convert (stream order).
__global__ __launch_bounds__(256) void k_hist(const int* __restrict__ labels,
                                              const float* __restrict__ rn2,
                                              int* __restrict__ cnt,
                                              float* __restrict__ bandmin) {
  __shared__ int h[NBINS];
  __shared__ int bm[2];
  const int t = threadIdx.x;
  if (t < NBINS) h[t] = 0;
  if (t < 2) bm[t] = 0x7f800000;
  __syncthreads();
  const int i = blockIdx.x * 256 + t;
  atomicAdd(&h[labels[i] & (NBINS - 1)], 1);
  atomicMin(&bm[t >> 7], __float_as_int(rn2[i]));
  __syncthreads();
  if (t < NBINS && h[t]) atomicAdd(&cnt[t], h[t]);
  if (t < 2) bandmin[blockIdx.x * 2 + t] = __int_as_float(bm[t]);
}

// Fused sim + masked exp-sum over the UPPER TRIANGLE of the band grid only
// (2080 of 4096 tiles): tile (band, ct) with ct >= band serves both
// orientations from the same acc — row side with seed rn2[row], col side
// (transposed, ct > band only) with seed rn2[col] into neg[] via atomics
// (rare path only; common case contributes exact f32 zeros).
//
// Work decomposition: pairing p handles bands p and 63-p: exactly 65 tiles.
// Stream q in [0,65): q < 64-p -> (band=p, ct=p+q); else (band=63-p, ct=q-1).
// Grid = 32 pairings x 16 segments (seg0 5 tiles, rest 4) = 512 blocks.
//
// LDS B-tile: logical (col, slot16B) at byte col*256 + (slot^(col&7))*16;
// linear LDS dest + inverse-swizzled GLOBAL source (rule 21) -> bank-balanced
// ds_read_b128. 2-phase double buffer, counted vmcnt, setprio around MFMA.
__global__ __launch_bounds__(256, 2) void k_main(
    const unsigned short* __restrict__ fb16, const int* __restrict__ labels,
    const float* __restrict__ rn2, const float* __restrict__ bandmin,
    float* __restrict__ neg) {
  __shared__ unsigned short lds[2][128 * 128];  // 2 x 32 KB

  const int tid = threadIdx.x;
  const int lane = tid & 63;
  const int wid = tid >> 6;
  const int wr = wid >> 1;
  const int wc = wid & 1;
  const int l15 = lane & 15;
  const int lhi = lane >> 4;
  const int l31 = lane & 31;
  const int lh32 = lane >> 5;

  const int p = (int)blockIdx.x >> 4;  // pairing
  const int s = (int)blockIdx.x & 15;  // segment
  const int qs = s * 4 + (s != 0);
  const int len = (s == 0) ? 5 : 4;

  auto decode = [&](int q, int& band_, int& ct_) {
    if (q < 64 - p) {
      band_ = p;
      ct_ = p + q;
    } else {
      band_ = 63 - p;
      ct_ = q - 1;
    }
  };

  // A fragments (32x32x16): lane holds A[l&31][(l>>5)*8 + e] per k-slice.
  bf16x8 a[2][8];
#define LOAD_A(bandv)                                                        \
  {                                                                          \
    _Pragma("unroll") for (int ri = 0; ri < 2; ++ri) {                       \
      const int row_ = (bandv) * 128 + wr * 64 + ri * 32 + l31;              \
      _Pragma("unroll") for (int ks = 0; ks < 8; ++ks)                       \
          a[ri][ks] = *reinterpret_cast<const bf16x8*>(                      \
              &fb16[row_ * K_DIM + ks * 16 + lh32 * 8]);                     \
    }                                                                        \
  }

  float s_st[2][16];
#pragma unroll
  for (int ri = 0; ri < 2; ++ri)
#pragma unroll
    for (int r = 0; r < 16; ++r) s_st[ri][r] = 0.f;

  // Row-side partial flush: wave-reduce over the 32 col-lanes, atomic-add
  // per row (s_st >= 0 and almost always exactly 0 -> no atomics issued).
#define FLUSH_S(bandv)                                                       \
  {                                                                          \
    float mxs_ = 0.f;                                                        \
    _Pragma("unroll") for (int ri = 0; ri < 2; ++ri)                         \
        _Pragma("unroll") for (int r = 0; r < 16; ++r)                       \
            mxs_ = fmaxf(mxs_, s_st[ri][r]);                                 \
    if (__any(mxs_ > 0.f)) {                                                 \
      _Pragma("unroll") for (int ri = 0; ri < 2; ++ri)                       \
          _Pragma("unroll") for (int r = 0; r < 16; ++r) {                   \
            float pv = s_st[ri][r];                                          \
            pv += __shfl_xor(pv, 1);                                         \
            pv += __shfl_xor(pv, 2);                                         \
            pv += __shfl_xor(pv, 4);                                         \
            pv += __shfl_xor(pv, 8);                                         \
            pv += __shfl_xor(pv, 16);                                        \
            if (l31 == 0 && pv > 0.f)                                        \
              atomicAdd(&neg[(bandv) * 128 + wr * 64 + ri * 32 + (r & 3) +   \
                             8 * (r >> 2) + 4 * lh32],                       \
                        pv);                                                 \
            s_st[ri][r] = 0.f;                                               \
          }                                                                  \
    }                                                                        \
  }

  // Staging: one 128x128 B-tile = 32 gload_lds (8 per wave), 1 KB each.
#define STAGE(buf, ctv)                                                      \
  {                                                                          \
    const int colT_ = (ctv) * 128;                                           \
    _Pragma("unroll") for (int it = 0; it < 8; ++it) {                       \
      const int col_ = wid * 32 + it * 4 + lhi;                              \
      gload_lds16(                                                           \
          &fb16[(colT_ + col_) * K_DIM + ((l15 ^ (col_ & 7)) << 3)],         \
          &lds[buf][wid * 4096 + it * 512]);                                 \
    }                                                                        \
  }

  int band, ct;
  decode(qs, band, ct);
  LOAD_A(band);

  // Per-tile flush thresholds, preloaded (static indexing via full unroll).
  float thrT[5];
#pragma unroll
  for (int qq = 0; qq < 5; ++qq) {
    if (qq < len) {
      int b_, c_;
      decode(qs + qq, b_, c_);
      thrT[qq] = (fminf(bandmin[b_], bandmin[c_]) - FLUSH_THR) * INV_C;
    } else {
      thrT[qq] = 0.f;
    }
  }

  STAGE(0, ct);

  int cur = 0;
#pragma unroll 5
  for (int qq = 0; qq < 5; ++qq) {
    if (qq >= len) break;
    const bool hasNext = (qq + 1 < len);
    int nband = band, nct = ct;
    if (hasNext) {
      decode(qs + qq + 1, nband, nct);
      STAGE(cur ^ 1, nct);
      asm volatile("s_waitcnt vmcnt(8)" ::: "memory");
    } else {
      asm volatile("s_waitcnt vmcnt(0)" ::: "memory");
    }
    __builtin_amdgcn_s_barrier();

    f32x16 acc[2][2];
#pragma unroll
    for (int ri = 0; ri < 2; ++ri)
#pragma unroll
      for (int cj = 0; cj < 2; ++cj)
#pragma unroll
        for (int e = 0; e < 16; ++e) acc[ri][cj][e] = 0.f;

    const unsigned short* bufp = &lds[cur][0];
    __builtin_amdgcn_s_setprio(1);
#pragma unroll
    for (int ks = 0; ks < 8; ++ks) {
      bf16x8 b[2];
#pragma unroll
      for (int cj = 0; cj < 2; ++cj) {
        const int col = wc * 64 + cj * 32 + l31;
        const int phys = (ks * 2 + lh32) ^ (col & 7);
        b[cj] = *reinterpret_cast<const bf16x8*>(&bufp[col * 128 + phys * 8]);
      }
#pragma unroll
      for (int ri = 0; ri < 2; ++ri)
#pragma unroll
        for (int cj = 0; cj < 2; ++cj)
          acc[ri][cj] = __builtin_amdgcn_mfma_f32_32x32x16_bf16(
              a[ri][ks], b[cj], acc[ri][cj], 0, 0, 0);
    }
    __builtin_amdgcn_s_setprio(0);
    __builtin_amdgcn_s_barrier();  // all waves done reading buf[cur]

    // Per-lane flush test (fmax trees fuse to v_max3).
    float mx = -INFINITY;
#pragma unroll
    for (int ri = 0; ri < 2; ++ri)
#pragma unroll
      for (int cj = 0; cj < 2; ++cj)
#pragma unroll
        for (int e = 0; e < 16; ++e) mx = fmaxf(mx, acc[ri][cj][e]);

    if (__any(mx >= thrT[qq])) {
      // Rare path: full masked exp2, BOTH orientations.
      // C/D layout: col = lane&31, row = (r&3) + 8*(r>>2) + 4*(lane>>5).
      const int colT = ct * 128 + wc * 64;
      const bool doCol = (ct != band);
      int clab[2];
      float cs[2];
#pragma unroll
      for (int cj = 0; cj < 2; ++cj) {
        clab[cj] = labels[colT + cj * 32 + l31];
        cs[cj] = rn2[colT + cj * 32 + l31];
      }
      float scol0 = 0.f, scol1 = 0.f;
#pragma unroll
      for (int ri = 0; ri < 2; ++ri) {
#pragma unroll
        for (int p4 = 0; p4 < 4; ++p4) {
          const int rbase = band * 128 + wr * 64 + ri * 32 + lh32 * 4 + p4 * 8;
          const float4 ms = *reinterpret_cast<const float4*>(&rn2[rbase]);
          const int4 rl = *reinterpret_cast<const int4*>(&labels[rbase]);
          const float msv[4] = {ms.x, ms.y, ms.z, ms.w};
          const int rlv[4] = {rl.x, rl.y, rl.z, rl.w};
#pragma unroll
          for (int q4 = 0; q4 < 4; ++q4) {
            const int r = p4 * 4 + q4;
#pragma unroll
            for (int cj = 0; cj < 2; ++cj) {
              const float v = acc[ri][cj][r] * C_LOG2;
              const bool differ = (clab[cj] != rlv[q4]);
              s_st[ri][r] += differ ? exp2f(v - msv[q4]) : 0.f;
              if (doCol) {
                const float e = differ ? exp2f(v - cs[cj]) : 0.f;
                if (cj == 0) scol0 += e;
                else scol1 += e;
              }
            }
          }
        }
      }
      if (doCol) {
        // Transposed side: sum over this wave's 64 rows (pair lh32 halves),
        // commit per col.
        scol0 += __shfl_xor(scol0, 32);
        scol1 += __shfl_xor(scol1, 32);
        if (lh32 == 0) {
          if (scol0 > 0.f) atomicAdd(&neg[colT + l31], scol0);
          if (scol1 > 0.f) atomicAdd(&neg[colT + 32 + l31], scol1);
        }
      }
    }

    if (hasNext && nband != band) {
      FLUSH_S(band);
      LOAD_A(nband);
    }
    band = nband;
    ct = nct;
    cur ^= 1;
  }
  FLUSH_S(band);
}

// Per-row loss -> global sums; last block finalizes the scalar.
__global__ __launch_bounds__(256) void k_merge(
    const float* __restrict__ neg, const int* __restrict__ cnt,
    const int* __restrict__ labels, const float* __restrict__ ious,
    float* __restrict__ sums, unsigned int* __restrict__ done,
    float* __restrict__ out) {
  const int row = blockIdx.x * 256 + threadIdx.x;
  const float ns = neg[row];
  int pc = cnt[labels[row] & (NBINS - 1)] - 1;
  if (pc < 1) pc = 1;  // reference always has pos_cnt >= 1 here; avoid 0/0
  const float loss = ns / (float)pc;  // LAMDA = 1; loss = -log_prob
  const bool keep = ious[row] >= 0.5f;
  float lv = keep ? loss : 0.f;
  float kv = keep ? 1.f : 0.f;
#pragma unroll
  for (int off = 32; off >= 1; off >>= 1) {
    lv += __shfl_xor(lv, off);
    kv += __shfl_xor(kv, off);
  }
  __shared__ float slv[4], skv[4];
  const int lane = threadIdx.x & 63, wv = threadIdx.x >> 6;
  if (lane == 0) {
    slv[wv] = lv;
    skv[wv] = kv;
  }
  __syncthreads();
  if (threadIdx.x == 0) {
    atomicAdd(&sums[0], slv[0] + slv[1] + slv[2] + slv[3]);
    atomicAdd(&sums[1], skv[0] + skv[1] + skv[2] + skv[3]);
    __threadfence();
    const unsigned int old = atomicAdd(done, 1u);
    if (old == (unsigned int)(M_ROWS / 256 - 1)) {
      const float a = atomicAdd(&sums[0], 0.f);  // atomic read (L2-coherent)
      const float b = atomicAdd(&sums[1], 0.f);
      out[0] = a / fmaxf(b, 1.f);
    }
  }
}

extern "C" void kernel_launch(void* const* d_in, const int* in_sizes, int n_in,
                              void* d_out, int out_size, void* d_ws,
                              size_t ws_size, hipStream_t stream) {
  const float* feat = (const float*)d_in[0];
  const int* labels = (const int*)d_in[1];
  const float* ious = (const float*)d_in[2];
  float* out = (float*)d_out;
  char* ws = (char*)d_ws;
  unsigned short* fb16 = (unsigned short*)(ws + FB16_OFF);
  float* rn2 = (float*)(ws + RN2_OFF);
  float* neg = (float*)(ws + NEG_OFF);
  float* bandmin = (float*)(ws + BMIN_OFF);
  int* cnt = (int*)(ws + CNT_OFF);
  float* sums = (float*)(ws + SUM_OFF);
  unsigned int* done = (unsigned int*)(ws + DONE_OFF);

  hipLaunchKernelGGL(k_convert, dim3(M_ROWS / 8), dim3(256), 0, stream, feat,
                     fb16, rn2, neg, cnt, sums, done);
  hipLaunchKernelGGL(k_hist, dim3(M_ROWS / 256), dim3(256), 0, stream, labels,
                     rn2, cnt, bandmin);
  hipLaunchKernelGGL(k_main, dim3(NPAIR * NSEG), dim3(256), 0, stream, fb16,
                     labels, rn2, bandmin, neg);
  hipLaunchKernelGGL(k_merge, dim3(M_ROWS / 256), dim3(256), 0, stream, neg,
                     cnt, labels, ious, sums, done, out);
}